// Round 12
// baseline (625.635 us; speedup 1.0000x reference)
//
#include <hip/hip_runtime.h>
#include <hip/hip_cooperative_groups.h>
#include <cstdint>
#include <cstddef>

namespace cg = cooperative_groups;

#define NN 50000
#define EE 640000
#define DD 128
#define LL 3
#define GG 256
#define LATD 64

typedef __attribute__((ext_vector_type(8))) __bf16 bf16x8;
typedef __attribute__((ext_vector_type(4))) float f32x4;

__device__ __forceinline__ unsigned short f2bf(float f) {
  __bf16 h = (__bf16)f;
  return __builtin_bit_cast(unsigned short, h);
}
__device__ __forceinline__ float bf2f(unsigned int u16) {
  unsigned int x = u16 << 16;
  return __builtin_bit_cast(float, x);
}
__device__ __forceinline__ void unpack8(uint4 v, float* f) {
  f[0] = bf2f(v.x & 0xffffu); f[1] = bf2f(v.x >> 16);
  f[2] = bf2f(v.y & 0xffffu); f[3] = bf2f(v.y >> 16);
  f[4] = bf2f(v.z & 0xffffu); f[5] = bf2f(v.z >> 16);
  f[6] = bf2f(v.w & 0xffffu); f[7] = bf2f(v.w >> 16);
}
__device__ __forceinline__ void acc8(uint4 v, float* f) {
  f[0] += bf2f(v.x & 0xffffu); f[1] += bf2f(v.x >> 16);
  f[2] += bf2f(v.y & 0xffffu); f[3] += bf2f(v.y >> 16);
  f[4] += bf2f(v.z & 0xffffu); f[5] += bf2f(v.z >> 16);
  f[6] += bf2f(v.w & 0xffffu); f[7] += bf2f(v.w >> 16);
}
__device__ __forceinline__ uint4 pack8(const float* f) {
  uint4 v;
  v.x = f2bf(f[0]) | ((unsigned)f2bf(f[1]) << 16);
  v.y = f2bf(f[2]) | ((unsigned)f2bf(f[3]) << 16);
  v.z = f2bf(f[4]) | ((unsigned)f2bf(f[5]) << 16);
  v.w = f2bf(f[6]) | ((unsigned)f2bf(f[7]) << 16);
  return v;
}

#define SWZ(byte_, row_) ((byte_) ^ (((row_) & 7) << 4))
#define CPAD 4   // counters: 1 int per 64B line (atomic line-serialization fix)

// ---------- cooperative build: cvt | wcvt | hist -> scan -> fill, one kernel ----------
// 1024 blocks x 256 thr, VGPR capped at 128 by (256,4) -> 4 blocks/CU co-resident.
__global__ __launch_bounds__(256, 4) void build_kernel(
    const float4* __restrict__ x, uint4* __restrict__ xb,
    const float* __restrict__ W1, const float* __restrict__ W2,
    uint4* __restrict__ wb,
    const int* __restrict__ src, const int* __restrict__ dstp,
    int* __restrict__ counts, int* __restrict__ rp,
    int* __restrict__ cursor, int* __restrict__ col,
    int* __restrict__ bsum) {
  cg::grid_group grid = cg::this_grid();
  __shared__ int ws[4];
  int b = blockIdx.x;
  int tid = b * 256 + (int)threadIdx.x;     // 0..262143
  int lane = threadIdx.x & 63, w = threadIdx.x >> 6;

  // phase 0a: x fp32 -> bf16 (800000 uint4)
  for (int t = tid; t < NN * DD / 8; t += 262144) {
    float4 a = x[t * 2], bb = x[t * 2 + 1];
    float f[8] = {a.x, a.y, a.z, a.w, bb.x, bb.y, bb.z, bb.w};
    xb[t] = pack8(f);
  }
  // phase 0b: weights fp32 -> bf16 pre-swizzled (12288 chunks)
  if (tid < 12288) {
    int m = tid >> 11;
    int q = tid & 2047;
    int byte = q * 16;
    int row = byte >> 8;
    int inner = byte & 255;
    int isrc = inner ^ ((row & 7) << 4);
    int k0 = isrc >> 1;
    const float* Wsrc = (m & 1) ? W2 : W1;
    const float* p = Wsrc + ((size_t)(m >> 1) * DD * DD + row * DD + k0);
    float4 f0 = ((const float4*)p)[0], f1 = ((const float4*)p)[1];
    float f[8] = {f0.x, f0.y, f0.z, f0.w, f1.x, f1.y, f1.z, f1.w};
    wb[(size_t)m * 2048 + q] = pack8(f);
  }
  // phase 0c: degree histogram (padded counters)
  for (int e = tid; e < EE; e += 262144) {
    atomicAdd(&counts[dstp[e] << CPAD], 1);
  }
  grid.sync();

  // phase 1: per-block 256-chunk scan (blocks 0..195)
  if (b < 196) {
    int i = b * 256 + (int)threadIdx.x;
    int v = (i < NN) ? counts[i << CPAD] : 0;
    int s = v;
#pragma unroll
    for (int off = 1; off < 64; off <<= 1) {
      int u = __shfl_up(s, off);
      if (lane >= off) s += u;
    }
    if (lane == 63) ws[w] = s;
    __syncthreads();
    int add = 0;
#pragma unroll
    for (int k = 0; k < 4; ++k) if (k < w) add += ws[k];
    int incl = s + add;
    if (i < NN) rp[i] = incl - v;
    if (threadIdx.x == 255) bsum[b] = incl;
  }
  grid.sync();

  // phase 2: scan bsum (block 0; 196 values)
  if (b == 0) {
    int t = threadIdx.x;
    int v = (t < 196) ? bsum[t] : 0;
    int s = v;
#pragma unroll
    for (int off = 1; off < 64; off <<= 1) {
      int u = __shfl_up(s, off);
      if (lane >= off) s += u;
    }
    __syncthreads();      // all ws reads from phase 1 done
    if (lane == 63) ws[w] = s;
    __syncthreads();
    int add = 0;
#pragma unroll
    for (int k = 0; k < 4; ++k) if (k < w) add += ws[k];
    int incl = s + add;
    if (t < 196) bsum[t] = incl - v;
  }
  grid.sync();

  // phase 3: apply block offsets -> row_ptr + cursor (blocks 0..195)
  if (b < 196) {
    int i = b * 256 + (int)threadIdx.x;
    if (i < NN) {
      int v = rp[i] + bsum[b];
      rp[i] = v;
      cursor[i << CPAD] = v;
    }
    if (i == 0) rp[NN] = EE;
  }
  grid.sync();

  // phase 4: CSR fill
  for (int e = tid; e < EE; e += 262144) {
    int p = atomicAdd(&cursor[dstp[e] << CPAD], 1);
    col[p] = src[e];
  }
}

// ---------- GIN aggregation: r7-proven — 16 lanes/node, 8-deep ILP, (256,4) ----------
__global__ __launch_bounds__(256, 4) void agg_kernel(const uint4* __restrict__ xin,
                                                     const int* __restrict__ row_ptr,
                                                     const int* __restrict__ colv,
                                                     uint4* __restrict__ agg, int n) {
  int tid = blockIdx.x * 256 + threadIdx.x;
  int node = tid >> 4;
  int c = tid & 15;
  if (node >= n) return;
  float acc[8];
  unpack8(xin[(size_t)node * 16 + c], acc);
  int s = row_ptr[node], e = row_ptr[node + 1];
  int j = s;
  for (; j + 8 <= e; j += 8) {
    int i0 = colv[j],     i1 = colv[j + 1], i2 = colv[j + 2], i3 = colv[j + 3];
    int i4 = colv[j + 4], i5 = colv[j + 5], i6 = colv[j + 6], i7 = colv[j + 7];
    uint4 v0 = xin[(size_t)i0 * 16 + c];
    uint4 v1 = xin[(size_t)i1 * 16 + c];
    uint4 v2 = xin[(size_t)i2 * 16 + c];
    uint4 v3 = xin[(size_t)i3 * 16 + c];
    uint4 v4 = xin[(size_t)i4 * 16 + c];
    uint4 v5 = xin[(size_t)i5 * 16 + c];
    uint4 v6 = xin[(size_t)i6 * 16 + c];
    uint4 v7 = xin[(size_t)i7 * 16 + c];
    acc8(v0, acc); acc8(v1, acc); acc8(v2, acc); acc8(v3, acc);
    acc8(v4, acc); acc8(v5, acc); acc8(v6, acc); acc8(v7, acc);
  }
  for (; j + 2 <= e; j += 2) {
    uint4 v0 = xin[(size_t)colv[j] * 16 + c];
    uint4 v1 = xin[(size_t)colv[j + 1] * 16 + c];
    acc8(v0, acc); acc8(v1, acc);
  }
  if (j < e) acc8(xin[(size_t)colv[j] * 16 + c], acc);
  agg[(size_t)node * 16 + c] = pack8(acc);
}

// ---------- barrier-free MFMA MLP (r11-proven) ----------
__global__ __launch_bounds__(512) void mlp_nb(
    const uint4* __restrict__ aggb, uint4* __restrict__ xout,
    const uint4* __restrict__ w1b, const uint4* __restrict__ w2b,
    const float* __restrict__ b1, const float* __restrict__ bng,
    const float* __restrict__ bnb, const float* __restrict__ bnm,
    const float* __restrict__ bnv, const float* __restrict__ b2) {
  __shared__ __align__(16) char smem[98304];
  char* w1p = smem;
  char* w2p = smem + 32768;
#pragma unroll
  for (int it = 0; it < 8; ++it) {
    int q = it * 512 + threadIdx.x;
    ((uint4*)w1p)[q] = w1b[q];
    ((uint4*)w2p)[q] = w2b[q];
  }
  int lane = threadIdx.x & 63;
  int c = lane & 15;
  int kq = lane >> 4;
  int wave = threadIdx.x >> 6;
  char* hs = smem + 65536 + wave * 4096;
  __syncthreads();

  float b1v[8], sv[8], tv[8], b2v[8];
#pragma unroll
  for (int ni = 0; ni < 8; ++ni) {
    int cc = ni * 16 + c;
    b1v[ni] = b1[cc];
    float s = bng[cc] * rsqrtf(bnv[cc] + 1e-5f);
    sv[ni] = s;
    tv[ni] = bnb[cc] - bnm[cc] * s;
    b2v[ni] = b2[cc];
  }

  for (int t = blockIdx.x * 8 + wave; t < NN / 16; t += 2048) {
    int base = t * 16;
    f32x4 acc[8];
#pragma unroll
    for (int ni = 0; ni < 8; ++ni) acc[ni] = (f32x4){0.f, 0.f, 0.f, 0.f};

#pragma unroll
    for (int ks = 0; ks < 4; ++ks) {
      bf16x8 a = *(const bf16x8*)(aggb + (size_t)(base + c) * 16 + ks * 4 + kq);
#pragma unroll
      for (int ni = 0; ni < 8; ++ni) {
        int wr = ni * 16 + c;
        bf16x8 bfr = *(const bf16x8*)(w1p + SWZ(wr * 256 + ks * 64 + kq * 16, wr));
        acc[ni] = __builtin_amdgcn_mfma_f32_16x16x32_bf16(a, bfr, acc[ni], 0, 0, 0);
      }
    }

#pragma unroll
    for (int ni = 0; ni < 8; ++ni)
#pragma unroll
      for (int r = 0; r < 4; ++r) {
        float h = acc[ni][r] + b1v[ni];
        h = h >= 0.f ? h : 0.2f * h;
        h = h * sv[ni] + tv[ni];
        int row = kq * 4 + r;
        *(__bf16*)(hs + row * 256 + SWZ((ni * 16 + c) * 2, row)) = (__bf16)h;
      }

#pragma unroll
    for (int ni = 0; ni < 8; ++ni) acc[ni] = (f32x4){0.f, 0.f, 0.f, 0.f};

#pragma unroll
    for (int ks = 0; ks < 4; ++ks) {
      bf16x8 a = *(const bf16x8*)(hs + c * 256 + SWZ(ks * 64 + kq * 16, c));
#pragma unroll
      for (int ni = 0; ni < 8; ++ni) {
        int wr = ni * 16 + c;
        bf16x8 bfr = *(const bf16x8*)(w2p + SWZ(wr * 256 + ks * 64 + kq * 16, wr));
        acc[ni] = __builtin_amdgcn_mfma_f32_16x16x32_bf16(a, bfr, acc[ni], 0, 0, 0);
      }
    }

#pragma unroll
    for (int ni = 0; ni < 8; ++ni)
#pragma unroll
      for (int r = 0; r < 4; ++r) {
        float xo = acc[ni][r] + b2v[ni];
        xo = xo >= 0.f ? xo : 0.2f * xo;
        int row = kq * 4 + r;
        *(__bf16*)(hs + row * 256 + (ni * 16 + c) * 2) = (__bf16)xo;
      }
#pragma unroll
    for (int it2 = 0; it2 < 4; ++it2) {
      int chunk = it2 * 64 + lane;
      uint4 v = *(const uint4*)(hs + chunk * 16);
      xout[(size_t)base * 16 + chunk] = v;
    }
  }
}

// ---------- head with inline pooling (r11-proven) ----------
__global__ __launch_bounds__(128) void head_kernel(
    const unsigned short* __restrict__ x, const int* __restrict__ batch,
    const float* __restrict__ og, const float* __restrict__ ob,
    const float* __restrict__ om, const float* __restrict__ ov,
    const float* __restrict__ fcW, const float* __restrict__ fcb,
    float* __restrict__ out) {
  __shared__ float pb[DD];
  __shared__ int slo, shi;
  int g = blockIdx.x;
  int t = threadIdx.x;
  if (t == 0) {
    int lo = 0, hi = NN;
    while (lo < hi) { int m = (lo + hi) >> 1; if (batch[m] < g) lo = m + 1; else hi = m; }
    slo = lo;
    lo = 0; hi = NN;
    while (lo < hi) { int m = (lo + hi) >> 1; if (batch[m] < g + 1) lo = m + 1; else hi = m; }
    shi = lo;
  }
  __syncthreads();
  float acc = 0.f;
  int node = slo;
  for (; node + 4 <= shi; node += 4) {
    float a0 = bf2f(x[(size_t)(node + 0) * DD + t]);
    float a1 = bf2f(x[(size_t)(node + 1) * DD + t]);
    float a2 = bf2f(x[(size_t)(node + 2) * DD + t]);
    float a3 = bf2f(x[(size_t)(node + 3) * DD + t]);
    acc += (a0 + a1) + (a2 + a3);
  }
  for (; node < shi; ++node) acc += bf2f(x[(size_t)node * DD + t]);
  float s = og[t] * rsqrtf(ov[t] + 1e-5f);
  pb[t] = (acc - om[t]) * s + ob[t];
  __syncthreads();
  if (t < LATD) {
    float a = fcb[t];
#pragma unroll 8
    for (int d = 0; d < DD; ++d) a = fmaf(fcW[t * DD + d], pb[d], a);
    out[(size_t)g * LATD + t] = a;
  }
}

extern "C" void kernel_launch(void* const* d_in, const int* in_sizes, int n_in,
                              void* d_out, int out_size, void* d_ws, size_t ws_size,
                              hipStream_t stream) {
  const float* x   = (const float*)d_in[0];
  const float* W1  = (const float*)d_in[1];
  const float* b1  = (const float*)d_in[2];
  const float* bng = (const float*)d_in[3];
  const float* bnb = (const float*)d_in[4];
  const float* bnm = (const float*)d_in[5];
  const float* bnv = (const float*)d_in[6];
  const float* W2  = (const float*)d_in[7];
  const float* b2  = (const float*)d_in[8];
  const float* og  = (const float*)d_in[9];
  const float* ob  = (const float*)d_in[10];
  const float* om  = (const float*)d_in[11];
  const float* ov  = (const float*)d_in[12];
  const float* fcW = (const float*)d_in[13];
  const float* fcb = (const float*)d_in[14];
  const int* ei    = (const int*)d_in[15];
  const int* batch = (const int*)d_in[16];
  const int* srcp = ei;
  const int* dstp = ei + EE;

  char* ws = (char*)d_ws;
  size_t off = 0;
  auto alloc = [&](size_t bytes) {
    void* p = ws + off;
    off += (bytes + 255) & ~(size_t)255;
    return p;
  };
  unsigned short* xb0  = (unsigned short*)alloc((size_t)NN * DD * 2);
  unsigned short* xb1  = (unsigned short*)alloc((size_t)NN * DD * 2);
  unsigned short* aggb = (unsigned short*)alloc((size_t)NN * DD * 2);
  uint4* wb     = (uint4*)alloc((size_t)6 * 2048 * 16);
  int* row_ptr  = (int*)alloc((NN + 1) * 4);
  int* cursor   = (int*)alloc((size_t)NN * 64);
  int* counts   = (int*)alloc((size_t)NN * 64);
  int* col      = (int*)alloc(EE * 4);
  int* bsum     = (int*)alloc(256 * 4);

  hipMemsetAsync(counts, 0, (size_t)NN * 64, stream);

  {
    const float4* x4 = (const float4*)x;
    uint4* xb0u = (uint4*)xb0;
    void* args[] = {
      (void*)&x4, (void*)&xb0u, (void*)&W1, (void*)&W2, (void*)&wb,
      (void*)&srcp, (void*)&dstp, (void*)&counts, (void*)&row_ptr,
      (void*)&cursor, (void*)&col, (void*)&bsum
    };
    hipLaunchCooperativeKernel((const void*)build_kernel, dim3(1024), dim3(256),
                               args, 0, stream);
  }

  unsigned short* xcur = xb0;
  unsigned short* xnext = xb1;
  for (int i = 0; i < LL; ++i) {
    agg_kernel<<<(NN * 16 + 255) / 256, 256, 0, stream>>>(
        (const uint4*)xcur, row_ptr, col, (uint4*)aggb, NN);
    mlp_nb<<<256, 512, 0, stream>>>(
        (const uint4*)aggb, (uint4*)xnext,
        wb + (size_t)i * 4096, wb + (size_t)i * 4096 + 2048,
        b1 + i * DD, bng + i * DD, bnb + i * DD, bnm + i * DD, bnv + i * DD,
        b2 + i * DD);
    unsigned short* t = xcur; xcur = xnext; xnext = t;
  }
  head_kernel<<<GG, 128, 0, stream>>>(
      xcur, batch, og, ob, om, ov, fcW, fcb, (float*)d_out);
}

// Round 13
// 219.815 us; speedup vs baseline: 2.8462x; 2.8462x over previous
//
#include <hip/hip_runtime.h>
#include <cstdint>
#include <cstddef>

#define NN 50000
#define EE 640000
#define DD 128
#define LL 3
#define GG 256
#define LATD 64

typedef __attribute__((ext_vector_type(8))) __bf16 bf16x8;
typedef __attribute__((ext_vector_type(4))) float f32x4;

__device__ __forceinline__ unsigned short f2bf(float f) {
  __bf16 h = (__bf16)f;
  return __builtin_bit_cast(unsigned short, h);
}
__device__ __forceinline__ float bf2f(unsigned int u16) {
  unsigned int x = u16 << 16;
  return __builtin_bit_cast(float, x);
}
__device__ __forceinline__ void unpack8(uint4 v, float* f) {
  f[0] = bf2f(v.x & 0xffffu); f[1] = bf2f(v.x >> 16);
  f[2] = bf2f(v.y & 0xffffu); f[3] = bf2f(v.y >> 16);
  f[4] = bf2f(v.z & 0xffffu); f[5] = bf2f(v.z >> 16);
  f[6] = bf2f(v.w & 0xffffu); f[7] = bf2f(v.w >> 16);
}
__device__ __forceinline__ void acc8(uint4 v, float* f) {
  f[0] += bf2f(v.x & 0xffffu); f[1] += bf2f(v.x >> 16);
  f[2] += bf2f(v.y & 0xffffu); f[3] += bf2f(v.y >> 16);
  f[4] += bf2f(v.z & 0xffffu); f[5] += bf2f(v.z >> 16);
  f[6] += bf2f(v.w & 0xffffu); f[7] += bf2f(v.w >> 16);
}
__device__ __forceinline__ uint4 pack8(const float* f) {
  uint4 v;
  v.x = f2bf(f[0]) | ((unsigned)f2bf(f[1]) << 16);
  v.y = f2bf(f[2]) | ((unsigned)f2bf(f[3]) << 16);
  v.z = f2bf(f[4]) | ((unsigned)f2bf(f[5]) << 16);
  v.w = f2bf(f[6]) | ((unsigned)f2bf(f[7]) << 16);
  return v;
}

#define SWZ(byte_, row_) ((byte_) ^ (((row_) & 7) << 4))
#define CPAD 4   // counters: 1 int per 64B line (atomic line-serialization fix)

// ---------- prep: x cvt | weights cvt pre-swizzled | degree hist (padded) ----------
#define CVT_BLK 3125
#define WCV_BLK 48
#define HIST_BLK 2500
__global__ __launch_bounds__(256) void prep_kernel(
    const float4* __restrict__ x, uint4* __restrict__ xb,
    const float* __restrict__ W1, const float* __restrict__ W2,
    uint4* __restrict__ wb, const int* __restrict__ dst,
    int* __restrict__ counts) {
  int b = blockIdx.x;
  if (b < CVT_BLK) {
    int t = b * 256 + threadIdx.x;
    float4 a = x[t * 2], bb = x[t * 2 + 1];
    float f[8] = {a.x, a.y, a.z, a.w, bb.x, bb.y, bb.z, bb.w};
    xb[t] = pack8(f);
  } else if (b < CVT_BLK + WCV_BLK) {
    int t = (b - CVT_BLK) * 256 + threadIdx.x;
    int m = t >> 11;
    int q = t & 2047;
    int byte = q * 16;
    int row = byte >> 8;
    int inner = byte & 255;
    int isrc = inner ^ ((row & 7) << 4);
    int k0 = isrc >> 1;
    const float* Wsrc = (m & 1) ? W2 : W1;
    const float* p = Wsrc + ((size_t)(m >> 1) * DD * DD + row * DD + k0);
    float4 f0 = ((const float4*)p)[0], f1 = ((const float4*)p)[1];
    float f[8] = {f0.x, f0.y, f0.z, f0.w, f1.x, f1.y, f1.z, f1.w};
    wb[(size_t)m * 2048 + q] = pack8(f);
  } else {
    int e = (b - CVT_BLK - WCV_BLK) * 256 + threadIdx.x;
    atomicAdd(&counts[dst[e] << CPAD], 1);
  }
}

// ---------- CSR scans ----------
__global__ __launch_bounds__(256) void scan1_kernel(const int* __restrict__ counts,
                                                    int* __restrict__ rp,
                                                    int* __restrict__ bsum, int n) {
  int i = blockIdx.x * 256 + threadIdx.x;
  int v = (i < n) ? counts[i << CPAD] : 0;
  int lane = threadIdx.x & 63, w = threadIdx.x >> 6;
  int s = v;
#pragma unroll
  for (int off = 1; off < 64; off <<= 1) {
    int u = __shfl_up(s, off);
    if (lane >= off) s += u;
  }
  __shared__ int ws[4];
  if (lane == 63) ws[w] = s;
  __syncthreads();
  int add = 0;
#pragma unroll
  for (int k = 0; k < 4; ++k) if (k < w) add += ws[k];
  int incl = s + add;
  if (i < n) rp[i] = incl - v;
  if (threadIdx.x == 255) bsum[blockIdx.x] = incl;
}

__global__ __launch_bounds__(256) void scan2_kernel(int* __restrict__ bsum, int nb) {
  int t = threadIdx.x;
  int v = (t < nb) ? bsum[t] : 0;
  int lane = t & 63, w = t >> 6;
  int s = v;
#pragma unroll
  for (int off = 1; off < 64; off <<= 1) {
    int u = __shfl_up(s, off);
    if (lane >= off) s += u;
  }
  __shared__ int ws[4];
  if (lane == 63) ws[w] = s;
  __syncthreads();
  int add = 0;
#pragma unroll
  for (int k = 0; k < 4; ++k) if (k < w) add += ws[k];
  int incl = s + add;
  if (t < nb) bsum[t] = incl - v;
}

__global__ __launch_bounds__(256) void scan3_kernel(int* __restrict__ rp,
                                                    int* __restrict__ cursor,
                                                    const int* __restrict__ bsum, int n) {
  int i = blockIdx.x * 256 + threadIdx.x;
  if (i < n) {
    int v = rp[i] + bsum[blockIdx.x];
    rp[i] = v;
    cursor[i << CPAD] = v;
  }
  if (i == 0) rp[n] = EE;
}

__global__ __launch_bounds__(256) void fill_kernel(const int* __restrict__ src,
                                                   const int* __restrict__ dst,
                                                   int* __restrict__ cursor,
                                                   int* __restrict__ col, int E) {
  int e = blockIdx.x * blockDim.x + threadIdx.x;
  if (e < E) {
    int p = atomicAdd(&cursor[dst[e] << CPAD], 1);
    col[p] = src[e];
  }
}

// ---------- GIN aggregation: r7-proven — 16 lanes/node, 8-deep ILP, (256,4) ----------
__global__ __launch_bounds__(256, 4) void agg_kernel(const uint4* __restrict__ xin,
                                                     const int* __restrict__ row_ptr,
                                                     const int* __restrict__ colv,
                                                     uint4* __restrict__ agg, int n) {
  int tid = blockIdx.x * 256 + threadIdx.x;
  int node = tid >> 4;
  int c = tid & 15;
  if (node >= n) return;
  float acc[8];
  unpack8(xin[(size_t)node * 16 + c], acc);
  int s = row_ptr[node], e = row_ptr[node + 1];
  int j = s;
  for (; j + 8 <= e; j += 8) {
    int i0 = colv[j],     i1 = colv[j + 1], i2 = colv[j + 2], i3 = colv[j + 3];
    int i4 = colv[j + 4], i5 = colv[j + 5], i6 = colv[j + 6], i7 = colv[j + 7];
    uint4 v0 = xin[(size_t)i0 * 16 + c];
    uint4 v1 = xin[(size_t)i1 * 16 + c];
    uint4 v2 = xin[(size_t)i2 * 16 + c];
    uint4 v3 = xin[(size_t)i3 * 16 + c];
    uint4 v4 = xin[(size_t)i4 * 16 + c];
    uint4 v5 = xin[(size_t)i5 * 16 + c];
    uint4 v6 = xin[(size_t)i6 * 16 + c];
    uint4 v7 = xin[(size_t)i7 * 16 + c];
    acc8(v0, acc); acc8(v1, acc); acc8(v2, acc); acc8(v3, acc);
    acc8(v4, acc); acc8(v5, acc); acc8(v6, acc); acc8(v7, acc);
  }
  for (; j + 2 <= e; j += 2) {
    uint4 v0 = xin[(size_t)colv[j] * 16 + c];
    uint4 v1 = xin[(size_t)colv[j + 1] * 16 + c];
    acc8(v0, acc); acc8(v1, acc);
  }
  if (j < e) acc8(xin[(size_t)colv[j] * 16 + c], acc);
  agg[(size_t)node * 16 + c] = pack8(acc);
}

// ---------- barrier-free MFMA MLP (r11-proven) ----------
__global__ __launch_bounds__(512) void mlp_nb(
    const uint4* __restrict__ aggb, uint4* __restrict__ xout,
    const uint4* __restrict__ w1b, const uint4* __restrict__ w2b,
    const float* __restrict__ b1, const float* __restrict__ bng,
    const float* __restrict__ bnb, const float* __restrict__ bnm,
    const float* __restrict__ bnv, const float* __restrict__ b2) {
  __shared__ __align__(16) char smem[98304];
  char* w1p = smem;
  char* w2p = smem + 32768;
#pragma unroll
  for (int it = 0; it < 8; ++it) {
    int q = it * 512 + threadIdx.x;
    ((uint4*)w1p)[q] = w1b[q];
    ((uint4*)w2p)[q] = w2b[q];
  }
  int lane = threadIdx.x & 63;
  int c = lane & 15;
  int kq = lane >> 4;
  int wave = threadIdx.x >> 6;
  char* hs = smem + 65536 + wave * 4096;
  __syncthreads();

  float b1v[8], sv[8], tv[8], b2v[8];
#pragma unroll
  for (int ni = 0; ni < 8; ++ni) {
    int cc = ni * 16 + c;
    b1v[ni] = b1[cc];
    float s = bng[cc] * rsqrtf(bnv[cc] + 1e-5f);
    sv[ni] = s;
    tv[ni] = bnb[cc] - bnm[cc] * s;
    b2v[ni] = b2[cc];
  }

  for (int t = blockIdx.x * 8 + wave; t < NN / 16; t += 2048) {
    int base = t * 16;
    f32x4 acc[8];
#pragma unroll
    for (int ni = 0; ni < 8; ++ni) acc[ni] = (f32x4){0.f, 0.f, 0.f, 0.f};

#pragma unroll
    for (int ks = 0; ks < 4; ++ks) {
      bf16x8 a = *(const bf16x8*)(aggb + (size_t)(base + c) * 16 + ks * 4 + kq);
#pragma unroll
      for (int ni = 0; ni < 8; ++ni) {
        int wr = ni * 16 + c;
        bf16x8 bfr = *(const bf16x8*)(w1p + SWZ(wr * 256 + ks * 64 + kq * 16, wr));
        acc[ni] = __builtin_amdgcn_mfma_f32_16x16x32_bf16(a, bfr, acc[ni], 0, 0, 0);
      }
    }

#pragma unroll
    for (int ni = 0; ni < 8; ++ni)
#pragma unroll
      for (int r = 0; r < 4; ++r) {
        float h = acc[ni][r] + b1v[ni];
        h = h >= 0.f ? h : 0.2f * h;
        h = h * sv[ni] + tv[ni];
        int row = kq * 4 + r;
        *(__bf16*)(hs + row * 256 + SWZ((ni * 16 + c) * 2, row)) = (__bf16)h;
      }

#pragma unroll
    for (int ni = 0; ni < 8; ++ni) acc[ni] = (f32x4){0.f, 0.f, 0.f, 0.f};

#pragma unroll
    for (int ks = 0; ks < 4; ++ks) {
      bf16x8 a = *(const bf16x8*)(hs + c * 256 + SWZ(ks * 64 + kq * 16, c));
#pragma unroll
      for (int ni = 0; ni < 8; ++ni) {
        int wr = ni * 16 + c;
        bf16x8 bfr = *(const bf16x8*)(w2p + SWZ(wr * 256 + ks * 64 + kq * 16, wr));
        acc[ni] = __builtin_amdgcn_mfma_f32_16x16x32_bf16(a, bfr, acc[ni], 0, 0, 0);
      }
    }

#pragma unroll
    for (int ni = 0; ni < 8; ++ni)
#pragma unroll
      for (int r = 0; r < 4; ++r) {
        float xo = acc[ni][r] + b2v[ni];
        xo = xo >= 0.f ? xo : 0.2f * xo;
        int row = kq * 4 + r;
        *(__bf16*)(hs + row * 256 + (ni * 16 + c) * 2) = (__bf16)xo;
      }
#pragma unroll
    for (int it2 = 0; it2 < 4; ++it2) {
      int chunk = it2 * 64 + lane;
      uint4 v = *(const uint4*)(hs + chunk * 16);
      xout[(size_t)base * 16 + chunk] = v;
    }
  }
}

// ---------- head with inline pooling (r11-proven) ----------
__global__ __launch_bounds__(128) void head_kernel(
    const unsigned short* __restrict__ x, const int* __restrict__ batch,
    const float* __restrict__ og, const float* __restrict__ ob,
    const float* __restrict__ om, const float* __restrict__ ov,
    const float* __restrict__ fcW, const float* __restrict__ fcb,
    float* __restrict__ out) {
  __shared__ float pb[DD];
  __shared__ int slo, shi;
  int g = blockIdx.x;
  int t = threadIdx.x;
  if (t == 0) {
    int lo = 0, hi = NN;
    while (lo < hi) { int m = (lo + hi) >> 1; if (batch[m] < g) lo = m + 1; else hi = m; }
    slo = lo;
    lo = 0; hi = NN;
    while (lo < hi) { int m = (lo + hi) >> 1; if (batch[m] < g + 1) lo = m + 1; else hi = m; }
    shi = lo;
  }
  __syncthreads();
  float acc = 0.f;
  int node = slo;
  for (; node + 4 <= shi; node += 4) {
    float a0 = bf2f(x[(size_t)(node + 0) * DD + t]);
    float a1 = bf2f(x[(size_t)(node + 1) * DD + t]);
    float a2 = bf2f(x[(size_t)(node + 2) * DD + t]);
    float a3 = bf2f(x[(size_t)(node + 3) * DD + t]);
    acc += (a0 + a1) + (a2 + a3);
  }
  for (; node < shi; ++node) acc += bf2f(x[(size_t)node * DD + t]);
  float s = og[t] * rsqrtf(ov[t] + 1e-5f);
  pb[t] = (acc - om[t]) * s + ob[t];
  __syncthreads();
  if (t < LATD) {
    float a = fcb[t];
#pragma unroll 8
    for (int d = 0; d < DD; ++d) a = fmaf(fcW[t * DD + d], pb[d], a);
    out[(size_t)g * LATD + t] = a;
  }
}

extern "C" void kernel_launch(void* const* d_in, const int* in_sizes, int n_in,
                              void* d_out, int out_size, void* d_ws, size_t ws_size,
                              hipStream_t stream) {
  const float* x   = (const float*)d_in[0];
  const float* W1  = (const float*)d_in[1];
  const float* b1  = (const float*)d_in[2];
  const float* bng = (const float*)d_in[3];
  const float* bnb = (const float*)d_in[4];
  const float* bnm = (const float*)d_in[5];
  const float* bnv = (const float*)d_in[6];
  const float* W2  = (const float*)d_in[7];
  const float* b2  = (const float*)d_in[8];
  const float* og  = (const float*)d_in[9];
  const float* ob  = (const float*)d_in[10];
  const float* om  = (const float*)d_in[11];
  const float* ov  = (const float*)d_in[12];
  const float* fcW = (const float*)d_in[13];
  const float* fcb = (const float*)d_in[14];
  const int* ei    = (const int*)d_in[15];
  const int* batch = (const int*)d_in[16];
  const int* src  = ei;
  const int* dstp = ei + EE;

  char* ws = (char*)d_ws;
  size_t off = 0;
  auto alloc = [&](size_t bytes) {
    void* p = ws + off;
    off += (bytes + 255) & ~(size_t)255;
    return p;
  };
  unsigned short* xb0  = (unsigned short*)alloc((size_t)NN * DD * 2);
  unsigned short* xb1  = (unsigned short*)alloc((size_t)NN * DD * 2);
  unsigned short* aggb = (unsigned short*)alloc((size_t)NN * DD * 2);
  uint4* wb     = (uint4*)alloc((size_t)6 * 2048 * 16);
  int* row_ptr  = (int*)alloc((NN + 1) * 4);
  int* cursor   = (int*)alloc((size_t)NN * 64);   // padded
  int* counts   = (int*)alloc((size_t)NN * 64);   // padded
  int* col      = (int*)alloc(EE * 4);
  int* bsum     = (int*)alloc(256 * 4);

  hipMemsetAsync(counts, 0, (size_t)NN * 64, stream);

  prep_kernel<<<CVT_BLK + WCV_BLK + HIST_BLK, 256, 0, stream>>>(
      (const float4*)x, (uint4*)xb0, W1, W2, wb, dstp, counts);

  const int NB = (NN + 255) / 256;  // 196
  scan1_kernel<<<NB, 256, 0, stream>>>(counts, row_ptr, bsum, NN);
  scan2_kernel<<<1, 256, 0, stream>>>(bsum, NB);
  scan3_kernel<<<NB, 256, 0, stream>>>(row_ptr, cursor, bsum, NN);
  fill_kernel<<<(EE + 255) / 256, 256, 0, stream>>>(src, dstp, cursor, col, EE);

  unsigned short* xcur = xb0;
  unsigned short* xnext = xb1;
  for (int i = 0; i < LL; ++i) {
    agg_kernel<<<(NN * 16 + 255) / 256, 256, 0, stream>>>(
        (const uint4*)xcur, row_ptr, col, (uint4*)aggb, NN);
    mlp_nb<<<256, 512, 0, stream>>>(
        (const uint4*)aggb, (uint4*)xnext,
        wb + (size_t)i * 4096, wb + (size_t)i * 4096 + 2048,
        b1 + i * DD, bng + i * DD, bnb + i * DD, bnm + i * DD, bnv + i * DD,
        b2 + i * DD);
    unsigned short* t = xcur; xcur = xnext; xnext = t;
  }
  head_kernel<<<GG, 128, 0, stream>>>(
      xcur, batch, og, ob, om, ov, fcW, fcb, (float*)d_out);
}